// Round 4
// baseline (246.418 us; speedup 1.0000x reference)
//
#include <hip/hip_runtime.h>

#define EPSL 1e-9f
#define NGROUPS 638976                 // 8192*26*3 groups of 31 floats
#define GPW 64                         // groups per wave-tile (1 per lane)
#define TFLOATS (GPW * 31)             // 1984 floats / tensor / tile (7936 B)
#define NTILES (NGROUPS / GPW)         // 9984
#define NBLOCKS 1248                   // 128-thread (2-wave) blocks
#define WPB 2                          // waves per block
#define NWAVES (NBLOCKS * WPB)         // 2496
#define NT (NTILES / NWAVES)           // 4 tiles per wave, exact
#define NSLOTS 64

// Reg-staged streaming pipeline (plain vector loads, NOT global_load_lds —
// the async-LDS DMA path capped effective BW at ~2.2-2.6 TB/s in r0/r3;
// the 6.3 TB/s copy ubench uses plain float4 loads). Per wave:
//   regs[t+2] <- global loads   (issued 2 tiles ahead, ~32KB in flight/wave)
//   LDS       <- regs[t]        (single buffer: LDS is only the transpose medium)
//   compute from LDS (stride-31 per-group reads, conflict-free)
// No barriers anywhere (per-wave private LDS slices) => no vmcnt(0) drain;
// compiler emits counted s_waitcnt itself. 31744 B/block -> 5 blocks/CU
// -> 10 waves/CU, 2.5 waves/SIMD for latency overlap.
struct Batch { float4 p[8]; float4 g[8]; };   // 16 float4/lane = one 16KB wave-tile

__global__ __launch_bounds__(128) void laneline_reduce_kernel(
    const float* __restrict__ pred,
    const float* __restrict__ gt,
    float* __restrict__ ws)
{
    __shared__ __align__(16) float sp[WPB][TFLOATS];   // per-wave slices, 15872 B
    __shared__ __align__(16) float sg[WPB][TFLOATS];

    const int lane = threadIdx.x & 63;
    const int wid  = threadIdx.x >> 6;
    const int wg   = blockIdx.x * WPB + wid;           // global wave id 0..2495

    Batch A, B;

    auto loadB = [&](int tile, Batch& b) {
        const float4* gp = (const float4*)(pred + (size_t)tile * TFLOATS) + lane;
        const float4* gg = (const float4*)(gt   + (size_t)tile * TFLOATS) + lane;
#pragma unroll
        for (int r = 0; r < 7; ++r) { b.p[r] = gp[r * 64]; b.g[r] = gg[r * 64]; }
        if (lane < 48) { b.p[7] = gp[448]; b.g[7] = gg[448]; }   // partial round
    };
    auto storeB = [&](const Batch& b) {
        float4* dp = (float4*)&sp[wid][0] + lane;
        float4* dg = (float4*)&sg[wid][0] + lane;
#pragma unroll
        for (int r = 0; r < 7; ++r) { dp[r * 64] = b.p[r]; dg[r * 64] = b.g[r]; }
        if (lane < 48) { dp[448] = b.p[7]; dg[448] = b.g[7]; }
    };

    float s0 = 0.f, s1 = 0.f, s2 = 0.f;
    auto compute = [&]() {
        // one 31-dim group per lane; stride 31 (odd) -> <=2 lanes/bank, free
        const float* lp = &sp[wid][lane * 31];
        const float* lg = &sg[wid][lane * 31];
        const float gcls = lg[30];
#pragma unroll
        for (int i = 0; i < 10; ++i) {
            const float gvis = lg[20 + i];
            // gt ~ U[0,1): gcls*gvis >= 0 so |w*(p-g)| = w*|p-g|
            s2 += gcls * gvis * (fabsf(lp[i]      - lg[i])
                               + fabsf(lp[10 + i] - lg[10 + i]));
            const float pv = lp[20 + i];
            s0 += gvis * __logf(pv + EPSL)
                + (1.0f - gvis + EPSL) * __logf(1.0f - pv + EPSL);
        }
        const float pc = lp[30];
        s1 += gcls * __logf(pc + EPSL)
            + (1.0f - gcls) * __logf(1.0f - pc + EPSL);
    };

    // depth-2 prologue: tiles t0,t1 in flight before first compute
    loadB(wg, A);
    loadB(wg + NWAVES, B);
#pragma unroll
    for (int it = 0; it < NT; ++it) {          // fully unrolled: all static idx
        Batch& cur = (it & 1) ? B : A;
        storeB(cur);                            // waits only cur's loads (counted)
        if (it + 2 < NT) loadB(wg + (it + 2) * NWAVES, cur);  // refill, 2 ahead
        compute();                              // lgkmcnt inserted by compiler
    }

    // ---- wave shuffle reduction, one atomic triple per wave ----
#pragma unroll
    for (int off = 32; off > 0; off >>= 1) {
        s0 += __shfl_down(s0, off, 64);
        s1 += __shfl_down(s1, off, 64);
        s2 += __shfl_down(s2, off, 64);
    }
    if (lane == 0) {
        float* slot = ws + (wg & (NSLOTS - 1)) * 16;   // 64 B stride
        atomicAdd(&slot[0], s0);
        atomicAdd(&slot[1], s1);
        atomicAdd(&slot[2], s2);
    }
}

__global__ __launch_bounds__(64) void laneline_finalize_kernel(
    const float* __restrict__ ws, float* __restrict__ out)
{
    const int t = threadIdx.x;
    float v0 = ws[t * 16], v1 = ws[t * 16 + 1], v2 = ws[t * 16 + 2];
#pragma unroll
    for (int off = 32; off > 0; off >>= 1) {
        v0 += __shfl_down(v0, off, 64);
        v1 += __shfl_down(v1, off, 64);
        v2 += __shfl_down(v2, off, 64);
    }
    if (t == 0) {
        const float l0 = -v0 * 0.1f;   // / NUM_Y_STEPS, negated
        const float l1 = -v1;
        const float l2 =  v2;
        out[0] = l0 + l1 + l2;
        out[1] = l0;
        out[2] = l1;
        out[3] = l2;
    }
}

extern "C" void kernel_launch(void* const* d_in, const int* in_sizes, int n_in,
                              void* d_out, int out_size, void* d_ws, size_t ws_size,
                              hipStream_t stream)
{
    const float* pred = (const float*)d_in[0];
    const float* gt   = (const float*)d_in[1];
    // d_in[2..5] (hcam/pitch) are unused by the reference computation.
    float* ws  = (float*)d_ws;
    float* out = (float*)d_out;

    hipMemsetAsync(ws, 0, NSLOTS * 16 * sizeof(float), stream);

    laneline_reduce_kernel<<<NBLOCKS, 128, 0, stream>>>(pred, gt, ws);
    laneline_finalize_kernel<<<1, 64, 0, stream>>>(ws, out);
}

// Round 5
// 192.048 us; speedup vs baseline: 1.2831x; 1.2831x over previous
//
#include <hip/hip_runtime.h>

#define EPSL 1e-9f
#define TFLOATS 1984                  // 64 groups x 31 floats per wave-tile
#define NTILES 9984                   // 638976 groups / 64
#define NBLOCKS 1248                  // 128-thread (2-wave) blocks
#define WPB 2                         // waves per block
#define NWAVES (NBLOCKS * WPB)        // 2496
#define NT 4                          // tiles per wave: 9984 / 2496 exact
#define NSLOTS 64

// Reg-staged streaming pipeline, spill-proof edition.
// Round-4 failure: Batch structs + reference-ternary defeated SROA ->
// 128 "registers" landed in scratch (VGPR=108, WRITE_SIZE=152MB). Fix:
// 32 individually NAMED float4 vars, hand-unrolled 4-tile pipeline via
// token-pasting macros - every access compile-time constant (rule #20).
// Structure: plain float4 global loads (the 6.3TB/s ubench path, NOT
// global_load_lds which capped at ~2.2-2.6TB/s in r0/r3), single
// per-wave LDS slice as transpose medium, depth-2 prefetch, zero
// barriers (block==2 waves but LDS slices are per-wave private);
// compiler emits counted vmcnt/lgkmcnt itself (G7).
// LDS 31744B/block -> 5 blocks/CU -> 10 waves/CU.

__global__ __launch_bounds__(128) void laneline_reduce_kernel(
    const float* __restrict__ pred,
    const float* __restrict__ gt,
    float* __restrict__ ws)
{
    __shared__ __align__(16) float sp[WPB][TFLOATS];   // 15872 B
    __shared__ __align__(16) float sg[WPB][TFLOATS];   // 15872 B

    const int lane = threadIdx.x & 63;
    const int wid  = threadIdx.x >> 6;
    const int wg   = blockIdx.x * WPB + wid;           // global wave id
    const bool full = (lane < 48);                     // tail round valid?

    // named register batches: 2 pipeline slots x 2 tensors x 8 float4
    float4 pa0,pa1,pa2,pa3,pa4,pa5,pa6,pa7;
    float4 ga0,ga1,ga2,ga3,ga4,ga5,ga6,ga7;
    float4 pb0,pb1,pb2,pb3,pb4,pb5,pb6,pb7;
    float4 gb0,gb1,gb2,gb3,gb4,gb5,gb6,gb7;

#define LOADT(p,g,tile) do{ \
    const float4* gp_ = (const float4*)(pred + (size_t)(tile) * TFLOATS) + lane; \
    const float4* gg_ = (const float4*)(gt   + (size_t)(tile) * TFLOATS) + lane; \
    p##0 = gp_[0];   p##1 = gp_[64];  p##2 = gp_[128]; p##3 = gp_[192]; \
    p##4 = gp_[256]; p##5 = gp_[320]; p##6 = gp_[384]; \
    g##0 = gg_[0];   g##1 = gg_[64];  g##2 = gg_[128]; g##3 = gg_[192]; \
    g##4 = gg_[256]; g##5 = gg_[320]; g##6 = gg_[384]; \
    if (full) { p##7 = gp_[448]; g##7 = gg_[448]; } \
}while(0)

#define STORET(p,g) do{ \
    float4* dp_ = (float4*)&sp[wid][0] + lane; \
    float4* dg_ = (float4*)&sg[wid][0] + lane; \
    dp_[0]   = p##0; dp_[64]  = p##1; dp_[128] = p##2; dp_[192] = p##3; \
    dp_[256] = p##4; dp_[320] = p##5; dp_[384] = p##6; \
    dg_[0]   = g##0; dg_[64]  = g##1; dg_[128] = g##2; dg_[192] = g##3; \
    dg_[256] = g##4; dg_[320] = g##5; dg_[384] = g##6; \
    if (full) { dp_[448] = p##7; dg_[448] = g##7; } \
}while(0)

    float s0 = 0.f, s1 = 0.f, s2 = 0.f;

    // one 31-float group per lane; stride 31 (odd) -> <=2 lanes/bank (free)
#define COMPUTE() do{ \
    const float* lp = &sp[wid][lane * 31]; \
    const float* lg = &sg[wid][lane * 31]; \
    const float gcls = lg[30]; \
    _Pragma("unroll") \
    for (int i = 0; i < 10; ++i) { \
        const float gvis = lg[20 + i]; \
        /* gt ~ U[0,1): gcls*gvis >= 0 so |w*(p-g)| = w*|p-g| */ \
        s2 += gcls * gvis * (fabsf(lp[i]      - lg[i]) \
                           + fabsf(lp[10 + i] - lg[10 + i])); \
        const float pv = lp[20 + i]; \
        s0 += gvis * __logf(pv + EPSL) \
            + (1.0f - gvis + EPSL) * __logf(1.0f - pv + EPSL); \
    } \
    const float pc = lp[30]; \
    s1 += gcls * __logf(pc + EPSL) \
        + (1.0f - gcls) * __logf(1.0f - pc + EPSL); \
}while(0)

    // ---- depth-2 pipeline over NT=4 tiles, fully explicit ----
    LOADT(pa,ga, wg);                   // tile 0 -> A
    LOADT(pb,gb, wg + NWAVES);          // tile 1 -> B

    STORET(pa,ga);                      // vmcnt waits only A's 16 loads
    LOADT(pa,ga, wg + 2*NWAVES);        // refill A with tile 2
    COMPUTE();                          // lgkmcnt only

    STORET(pb,gb);
    LOADT(pb,gb, wg + 3*NWAVES);        // refill B with tile 3
    COMPUTE();

    STORET(pa,ga);
    COMPUTE();

    STORET(pb,gb);
    COMPUTE();

#undef LOADT
#undef STORET
#undef COMPUTE

    // ---- wave shuffle reduction, one atomic triple per wave ----
#pragma unroll
    for (int off = 32; off > 0; off >>= 1) {
        s0 += __shfl_down(s0, off, 64);
        s1 += __shfl_down(s1, off, 64);
        s2 += __shfl_down(s2, off, 64);
    }
    if (lane == 0) {
        float* slot = ws + (wg & (NSLOTS - 1)) * 16;   // 64 B stride
        atomicAdd(&slot[0], s0);
        atomicAdd(&slot[1], s1);
        atomicAdd(&slot[2], s2);
    }
}

__global__ __launch_bounds__(64) void laneline_finalize_kernel(
    const float* __restrict__ ws, float* __restrict__ out)
{
    const int t = threadIdx.x;
    float v0 = ws[t * 16], v1 = ws[t * 16 + 1], v2 = ws[t * 16 + 2];
#pragma unroll
    for (int off = 32; off > 0; off >>= 1) {
        v0 += __shfl_down(v0, off, 64);
        v1 += __shfl_down(v1, off, 64);
        v2 += __shfl_down(v2, off, 64);
    }
    if (t == 0) {
        const float l0 = -v0 * 0.1f;   // / NUM_Y_STEPS, negated
        const float l1 = -v1;
        const float l2 =  v2;
        out[0] = l0 + l1 + l2;
        out[1] = l0;
        out[2] = l1;
        out[3] = l2;
    }
}

extern "C" void kernel_launch(void* const* d_in, const int* in_sizes, int n_in,
                              void* d_out, int out_size, void* d_ws, size_t ws_size,
                              hipStream_t stream)
{
    const float* pred = (const float*)d_in[0];
    const float* gt   = (const float*)d_in[1];
    // d_in[2..5] (hcam/pitch) are unused by the reference computation.
    float* ws  = (float*)d_ws;
    float* out = (float*)d_out;

    hipMemsetAsync(ws, 0, NSLOTS * 16 * sizeof(float), stream);

    laneline_reduce_kernel<<<NBLOCKS, 128, 0, stream>>>(pred, gt, ws);
    laneline_finalize_kernel<<<1, 64, 0, stream>>>(ws, out);
}